// Round 5
// baseline (238.112 us; speedup 1.0000x reference)
//
#include <hip/hip_runtime.h>
#include <hip/hip_bf16.h>
#include <math.h>

// Problem constants
#define BB   32
#define HH   40
#define WW   256
#define NF   40          // FREQ
#define H1N  36
#define W1N  252
#define KCNN 580608      // 64*36*252
#define NBLK2 504        // k2 blocks (x4 waves = 2016 slices)
#define KPW  288         // k per wave slice; 2016*288 == KCNN exactly

typedef __attribute__((ext_vector_type(8))) short bf16x8;   // 8 bf16 = 4 VGPRs
typedef __attribute__((ext_vector_type(4))) float f32x4;    // MFMA C/D

static __device__ __forceinline__ unsigned short f2bf(float v) {
    __hip_bfloat16 h = __float2bfloat16(v);
    return *(unsigned short*)&h;
}

static __device__ __forceinline__ bf16x8 packbf(float4 lo, float4 hi) {
    bf16x8 r;
    r[0] = (short)f2bf(lo.x); r[1] = (short)f2bf(lo.y);
    r[2] = (short)f2bf(lo.z); r[3] = (short)f2bf(lo.w);
    r[4] = (short)f2bf(hi.x); r[5] = (short)f2bf(hi.y);
    r[6] = (short)f2bf(hi.z); r[7] = (short)f2bf(hi.w);
    return r;
}

// ---------------- K0: w1 -> w1c [tap][c1][c0] bf16; also zero gacc/done ----------------
__global__ void k0_prep(const float* __restrict__ w1, unsigned short* __restrict__ w1c,
                        float* __restrict__ gacc, unsigned int* __restrict__ done) {
    int o = blockIdx.x * 256 + threadIdx.x;   // 72*256 = 18432 = 9*64*32
    int c0  = o & 31;
    int c1  = (o >> 5) & 63;
    int tap = o >> 11;                        // 0..8
    w1c[o] = f2bf(w1[(c1 * 32 + c0) * 9 + tap]);
    if (blockIdx.x == 71) {
        for (int p = threadIdx.x; p < 1280; p += 256) gacc[p] = 0.0f;
        if (threadIdx.x == 0) *done = 0u;
    }
}

// ---------------- K1: fused conv0(relu) + conv1(relu) via bf16 MFMA -> x (bf16) --------
// grid (4 jt, 9 it, 32 b), block 256 (4 waves). Wave w owns output row i0+w.
// Phase A: input tile -> LDS. Phase B: conv0 register-rotation strips (b128/b64 LDS
// reads, ~2.5x fewer LDS ops than per-output reads) -> y0T bf16 [pos][c0 pad40].
// Phase C: conv1 = 9 tap-GEMMs K=32 via MFMA. Phase D: LDS transpose epilogue ->
// coalesced uint2 global stores.
__global__ __launch_bounds__(256) void k1_conv(
        const float* __restrict__ inp, const float* __restrict__ w0,
        const float* __restrict__ b0, const unsigned short* __restrict__ w1c,
        const float* __restrict__ b1, unsigned short* __restrict__ xbf) {
    __shared__ __align__(16) unsigned short smem[18432];   // 36864 B, 3 aliased uses
    unsigned short* y0T = smem;                   // [pos 396][c0 pad40] bf16
    float* ins = (float*)(smem + 15840);          // [8][68] + 2 pad f32
    unsigned short* xp = smem;                    // phase D: [c1][ci][72] bf16

    const int jt = blockIdx.x;        // j0 = 64*jt
    const int it = blockIdx.y;        // i0 = 4*it
    const int b  = blockIdx.z;
    const int i0 = it * 4;
    const int j0 = jt * 64;
    const int tid = threadIdx.x;

    // ---- A: stage input rows i0..i0+7, cols j0..j0+67 (+2 pad) ----
    for (int s = tid; s < 546; s += 256) {
        int r = s / 68, c = s - r * 68;
        float v = 0.0f;
        if (r < 8 && (j0 + c) < WW) v = inp[(b * HH + i0 + r) * WW + j0 + c];
        ins[s] = v;
    }
    __syncthreads();

    // ---- B: conv0 -> y0T, register-rotation strips of 4 cols ----
    {
        const int c0  = tid & 31;
        const int sub = tid >> 5;     // 0..7
        float wreg[9];
        #pragma unroll
        for (int k = 0; k < 9; ++k) wreg[k] = w0[c0 * 9 + k];
        const float bias = b0[c0];
        for (int s = sub; s < 17; s += 8) {
            const int cbase = 4 * s;
            float rows[3][6];
            #pragma unroll
            for (int r = 0; r < 8; ++r) {
                {
                    const float4 a  = *(const float4*)&ins[r * 68 + cbase];
                    const float2 b2 = *(const float2*)&ins[r * 68 + cbase + 4];
                    float* dst = rows[r % 3];
                    dst[0] = a.x; dst[1] = a.y; dst[2] = a.z;
                    dst[3] = a.w; dst[4] = b2.x; dst[5] = b2.y;
                }
                if (r >= 2) {
                    const int ro = r - 2;
                    const float* r0 = rows[ro % 3];
                    const float* r1 = rows[(ro + 1) % 3];
                    const float* r2 = rows[(ro + 2) % 3];
                    #pragma unroll
                    for (int c = 0; c < 4; ++c) {
                        const int colg = cbase + c;
                        if (colg < 66) {
                            float v = 0.0f;
                            if (j0 + colg < 254) {
                                float a = bias;
                                a = fmaf(r0[c],     wreg[0], a);
                                a = fmaf(r0[c + 1], wreg[1], a);
                                a = fmaf(r0[c + 2], wreg[2], a);
                                a = fmaf(r1[c],     wreg[3], a);
                                a = fmaf(r1[c + 1], wreg[4], a);
                                a = fmaf(r1[c + 2], wreg[5], a);
                                a = fmaf(r2[c],     wreg[6], a);
                                a = fmaf(r2[c + 1], wreg[7], a);
                                a = fmaf(r2[c + 2], wreg[8], a);
                                v = fmaxf(a, 0.0f);
                            }
                            y0T[(ro * 66 + colg) * 40 + c0] = f2bf(v);
                        }
                    }
                }
            }
        }
    }
    __syncthreads();

    // ---- C: conv1, 9 tap-GEMMs K=32. A = w1c (L1-hot global), B = y0T (LDS) ----
    const int w    = tid >> 6;        // wave id -> output row i0+w
    const int lane = tid & 63;
    const int l15  = lane & 15;
    const int quad = lane >> 4;

    float biasr[4][4];
    #pragma unroll
    for (int mt = 0; mt < 4; ++mt)
        #pragma unroll
        for (int rg = 0; rg < 4; ++rg)
            biasr[mt][rg] = b1[mt * 16 + quad * 4 + rg];

    f32x4 acc[4][4];                  // [mt(ch)][nt(pos)]
    #pragma unroll
    for (int mt = 0; mt < 4; ++mt)
        #pragma unroll
        for (int nt = 0; nt < 4; ++nt)
            acc[mt][nt] = (f32x4){0.f, 0.f, 0.f, 0.f};

    #pragma unroll
    for (int ki = 0; ki < 3; ++ki) {
        #pragma unroll
        for (int kj = 0; kj < 3; ++kj) {
            const int tap = ki * 3 + kj;
            bf16x8 af[4], bfr[4];
            #pragma unroll
            for (int mt = 0; mt < 4; ++mt)
                af[mt] = *(const bf16x8*)(w1c + ((tap * 64 + mt * 16 + l15) * 32 + quad * 8));
            #pragma unroll
            for (int nt = 0; nt < 4; ++nt)
                bfr[nt] = *(const bf16x8*)(y0T + (((w + ki) * 66 + nt * 16 + l15 + kj) * 40 + quad * 8));
            #pragma unroll
            for (int mt = 0; mt < 4; ++mt)
                #pragma unroll
                for (int nt = 0; nt < 4; ++nt)
                    acc[mt][nt] = __builtin_amdgcn_mfma_f32_16x16x32_bf16(
                        af[mt], bfr[nt], acc[mt][nt], 0, 0, 0);
        }
    }
    __syncthreads();                  // y0T reads complete before xp overwrite

    // ---- D: relu(x+b1) -> LDS transpose -> coalesced stores ----
    #pragma unroll
    for (int nt = 0; nt < 4; ++nt) {
        const int j = nt * 16 + l15;
        #pragma unroll
        for (int mt = 0; mt < 4; ++mt) {
            #pragma unroll
            for (int rg = 0; rg < 4; ++rg) {
                const int c1 = mt * 16 + quad * 4 + rg;
                const float v = fmaxf(acc[mt][nt][rg] + biasr[mt][rg], 0.0f);
                xp[(c1 * 4 + w) * 72 + j] = f2bf(v);
            }
        }
    }
    __syncthreads();
    {
        const int chunk = tid & 7;
        const int rb    = tid >> 3;
        #pragma unroll
        for (int p = 0; p < 8; ++p) {
            const int rowid = rb + 32 * p;
            const int c1 = rowid >> 2, ci = rowid & 3;
            uint4 v = *(const uint4*)&xp[rowid * 72 + chunk * 8];
            const int gj = j0 + chunk * 8;
            unsigned short* gp = xbf + (size_t)b * KCNN
                               + (size_t)(c1 * H1N + i0 + ci) * W1N + gj;
            uint2 lo; lo.x = v.x; lo.y = v.y;
            if (gj + 8 <= W1N) {
                uint2 hi; hi.x = v.z; hi.y = v.w;
                *(uint2*)gp = lo;
                *(uint2*)(gp + 4) = hi;
            } else if (gj < W1N) {    // jt==3, chunk==7: shorts 248..251
                *(uint2*)gp = lo;
            }
        }
    }
}

// ---------------- K2: barrier-free MFMA split-K GEMM + fused gate epilogue ----------------
// 504 blocks x 4 waves; each wave owns a private 288-k slice (9 chunks x 32).
// Per chunk: 2 A-loads (x bf16) + 6 B-loads (wr f32 -> bf16) + 6 MFMA. No barriers
// in the k-loop. Block reduce -> atomics into gacc; LAST block (done-counter) computes
// sigmoid gates + wtd_mean (k3 fused).
__global__ __launch_bounds__(256) void k2_gemm(
        const unsigned short* __restrict__ xbf, const float* __restrict__ wr,
        const float* __restrict__ br, float* __restrict__ gacc,
        unsigned int* __restrict__ done, float* __restrict__ gates,
        float* __restrict__ out) {
    __shared__ float red[4][32][41];  // wave-partials, stride 41 breaks conflicts
    __shared__ unsigned int lastf;

    const int tid  = threadIdx.x;
    const int wv   = tid >> 6;
    const int lane = tid & 63;
    const int l15  = lane & 15;
    const int quad = lane >> 4;
    const size_t kw = (size_t)(blockIdx.x * 4 + wv) * KPW;

    const unsigned short* ap0 = xbf + (size_t)l15 * KCNN + kw + quad * 8;
    const unsigned short* ap1 = ap0 + (size_t)16 * KCNN;
    const float* bp0 = wr + (size_t)l15 * KCNN + kw + quad * 8;
    const float* bp1 = bp0 + (size_t)16 * KCNN;
    const int r2 = (l15 < 8) ? (32 + l15) : 39;       // clamp: cols>=40 discarded later
    const float* bp2 = wr + (size_t)r2 * KCNN + kw + quad * 8;

    f32x4 acc[2][3];
    #pragma unroll
    for (int mt = 0; mt < 2; ++mt)
        #pragma unroll
        for (int nt = 0; nt < 3; ++nt)
            acc[mt][nt] = (f32x4){0.f, 0.f, 0.f, 0.f};

    bf16x8 a0c, a1c, a0n, a1n;
    float4 bw[3][2], bwn[3][2];

    a0c = *(const bf16x8*)ap0;
    a1c = *(const bf16x8*)ap1;
    bw[0][0] = *(const float4*)bp0; bw[0][1] = *(const float4*)(bp0 + 4);
    bw[1][0] = *(const float4*)bp1; bw[1][1] = *(const float4*)(bp1 + 4);
    bw[2][0] = *(const float4*)bp2; bw[2][1] = *(const float4*)(bp2 + 4);

    for (int c = 0; c < 9; ++c) {
        if (c < 8) {                  // prefetch next chunk; overlaps MFMA below
            const int o2 = (c + 1) * 32;
            a0n = *(const bf16x8*)(ap0 + o2);
            a1n = *(const bf16x8*)(ap1 + o2);
            bwn[0][0] = *(const float4*)(bp0 + o2); bwn[0][1] = *(const float4*)(bp0 + o2 + 4);
            bwn[1][0] = *(const float4*)(bp1 + o2); bwn[1][1] = *(const float4*)(bp1 + o2 + 4);
            bwn[2][0] = *(const float4*)(bp2 + o2); bwn[2][1] = *(const float4*)(bp2 + o2 + 4);
        }
        #pragma unroll
        for (int nt = 0; nt < 3; ++nt) {
            bf16x8 bfrag = packbf(bw[nt][0], bw[nt][1]);
            acc[0][nt] = __builtin_amdgcn_mfma_f32_16x16x32_bf16(a0c, bfrag, acc[0][nt], 0, 0, 0);
            acc[1][nt] = __builtin_amdgcn_mfma_f32_16x16x32_bf16(a1c, bfrag, acc[1][nt], 0, 0, 0);
        }
        if (c < 8) {
            a0c = a0n; a1c = a1n;
            #pragma unroll
            for (int nt = 0; nt < 3; ++nt) { bw[nt][0] = bwn[nt][0]; bw[nt][1] = bwn[nt][1]; }
        }
    }

    // ---- block reduce 4 waves -> atomics ----
    #pragma unroll
    for (int mt = 0; mt < 2; ++mt)
        #pragma unroll
        for (int nt = 0; nt < 3; ++nt)
            #pragma unroll
            for (int rg = 0; rg < 4; ++rg) {
                int bb = mt * 16 + quad * 4 + rg;
                int ff = nt * 16 + l15;
                if (ff < NF) red[wv][bb][ff] = acc[mt][nt][rg];
            }
    __syncthreads();
    for (int p = tid; p < 1280; p += 256) {
        int bb = p / 40, ff = p - bb * 40;
        atomicAdd(gacc + p, red[0][bb][ff] + red[1][bb][ff] + red[2][bb][ff] + red[3][bb][ff]);
    }
    __syncthreads();                  // drain all atomics before done-increment

    if (tid == 0) {
        __threadfence();              // release: our gacc adds visible before count
        lastf = (atomicAdd(done, 1u) == NBLK2 - 1) ? 1u : 0u;
    }
    __syncthreads();
    if (lastf) {                      // ---- fused k3: gates + wtd_mean ----
        __threadfence();              // acquire
        float part = 0.0f;
        for (int p = tid; p < 1280; p += 256) {
            float s = __hip_atomic_load(gacc + p, __ATOMIC_RELAXED, __HIP_MEMORY_SCOPE_AGENT);
            int f = p % 40;
            float g = 1.0f / (1.0f + __expf(-(s + br[f])));
            gates[p] = g;
            part += g * 2.0f * (float)(f + 1);
        }
        #pragma unroll
        for (int off = 32; off >= 1; off >>= 1) part += __shfl_xor(part, off);
        float* redf = (float*)red;
        if ((tid & 63) == 0) redf[tid >> 6] = part;
        __syncthreads();
        if (tid == 0)
            out[51200] = (redf[0] + redf[1] + redf[2] + redf[3]) * (1.0f / 1280.0f);
    }
}

// ---------------- K4: feats (inline) -> sin/cos projection -> mods ----------------
__global__ __launch_bounds__(320) void k4_mods(
        const float* __restrict__ inp, const float* __restrict__ wf,
        const float* __restrict__ bfp, const float* __restrict__ gates,
        float* __restrict__ out) {
    const int f = blockIdx.x, b = blockIdx.y;
    const int tid = threadIdx.x;
    const int h  = tid >> 3;
    const int wl = tid & 7;
    float wfv[5];
    #pragma unroll
    for (int t = 0; t < 5; ++t) wfv[t] = wf[t];
    const float bias = bfp[0];
    const float cph = 6.283185307179586f * (float)(f + 1) / 255.0f;
    const float* row = inp + (b * HH + h) * WW;
    float sa = 0.0f, ca = 0.0f;
    for (int m = 0; m < 32; ++m) {
        int w = wl + 8 * m;
        float feat = bias;
        #pragma unroll
        for (int d = -2; d <= 2; ++d) {
            int wc = w + d;
            if (wc >= 0 && wc < WW) feat = fmaf(row[wc], wfv[d + 2], feat);
        }
        float sv, cv;
        __sincosf(cph * (float)w, &sv, &cv);
        sa = fmaf(sv, feat, sa);
        ca = fmaf(cv, feat, ca);
    }
    #pragma unroll
    for (int off = 4; off >= 1; off >>= 1) {
        sa += __shfl_xor(sa, off, 8);
        ca += __shfl_xor(ca, off, 8);
    }
    if (wl == 0) {
        float mag = sqrtf(sa * sa + ca * ca) * (1.0f / 256.0f);
        out[b * 1600 + f * 40 + h] = mag * gates[b * 40 + f];
    }
}

extern "C" void kernel_launch(void* const* d_in, const int* in_sizes, int n_in,
                              void* d_out, int out_size, void* d_ws, size_t ws_size,
                              hipStream_t stream) {
    const float* inp = (const float*)d_in[0];
    const float* w0  = (const float*)d_in[1];
    const float* b0  = (const float*)d_in[2];
    const float* w1  = (const float*)d_in[3];
    const float* b1  = (const float*)d_in[4];
    const float* wf  = (const float*)d_in[5];
    const float* bf_ = (const float*)d_in[6];
    const float* wr  = (const float*)d_in[7];
    const float* br  = (const float*)d_in[8];
    float* out = (float*)d_out;

    char* ws = (char*)d_ws;
    unsigned short* xbf = (unsigned short*)ws;               // 37,158,912 B
    unsigned short* w1c = (unsigned short*)(ws + 37158912);  // 36,864 B
    float* gacc  = (float*)(ws + 37195776);                  // 5,120 B
    float* gates = (float*)(ws + 37200896);                  // 5,120 B
    unsigned int* done = (unsigned int*)(ws + 37206016);     // 4 B

    k0_prep<<<72, 256, 0, stream>>>(w1, w1c, gacc, done);
    k1_conv<<<dim3(4, 9, 32), 256, 0, stream>>>(inp, w0, b0, w1c, b1, xbf);
    k2_gemm<<<NBLK2, 256, 0, stream>>>(xbf, wr, br, gacc, done, gates, out);
    k4_mods<<<dim3(40, 32), 320, 0, stream>>>(inp, wf, bf_, gates, out);
}